// Round 1
// baseline (681.417 us; speedup 1.0000x reference)
//
#include <hip/hip_runtime.h>

typedef _Float16 f16x8 __attribute__((ext_vector_type(8)));
typedef _Float16 f16x4 __attribute__((ext_vector_type(4)));
typedef float    f32x4 __attribute__((ext_vector_type(4)));

#define MFMA(a,b,c) __builtin_amdgcn_mfma_f32_16x16x32_f16((a),(b),(c),0,0,0)

// ---------------- prep: fold weights ----------------
// ws layout (bytes): [0)      Wk~ f16 [128][128]  (scale folded)
//                    [32768)  Wq  f16 [128][128]
//                    [65536)  Wv' f16 [128][128]  (Wo @ Wv)
//                    [98304)  biases f32: bk~[128], bq[128], b'[128]
__global__ __launch_bounds__(128) void prep_kernel(
    const float* __restrict__ Wk, const float* __restrict__ bk,
    const float* __restrict__ Wq, const float* __restrict__ bq,
    const float* __restrict__ Wv, const float* __restrict__ bv,
    const float* __restrict__ Wo, const float* __restrict__ bo,
    _Float16* __restrict__ wh, float* __restrict__ bf) {
  const int o = blockIdx.x;
  const int c = threadIdx.x;
  const float scale = 0.08838834764831844f;  // 1/sqrt(128)
  float acc = 0.f;
  for (int m = 0; m < 128; ++m) acc += Wo[o*128+m] * Wv[m*128+c];
  wh[o*128+c]         = (_Float16)(Wk[o*128+c] * scale);
  wh[16384 + o*128+c] = (_Float16)(Wq[o*128+c]);
  wh[32768 + o*128+c] = (_Float16)acc;
  if (c == 0) {
    float a2 = 0.f;
    for (int m = 0; m < 128; ++m) a2 += Wo[o*128+m] * bv[m];
    bf[o]       = bk[o] * scale;
    bf[128 + o] = bq[o];
    bf[256 + o] = a2 + bo[o];
  }
}

__device__ __forceinline__ f16x4 cvt4(f32x4 v, f32x4 b) {
  f16x4 r;
  r[0] = (_Float16)(v[0] + b[0]); r[1] = (_Float16)(v[1] + b[1]);
  r[2] = (_Float16)(v[2] + b[2]); r[3] = (_Float16)(v[3] + b[3]);
  return r;
}
__device__ __forceinline__ f16x4 cvt4z(f32x4 v) {
  f16x4 r;
  r[0] = (_Float16)v[0]; r[1] = (_Float16)v[1];
  r[2] = (_Float16)v[2]; r[3] = (_Float16)v[3];
  return r;
}

// ---------------- fused attention ----------------
// grid = 256 blocks x 1024 thr. Block bb handles 8 consecutive pixel-groups
// (P=4 consecutive w each) => 32 consecutive w of one (b,h) row: every 64B
// x/out line belongs to exactly one block.
__global__ __launch_bounds__(1024) void attn_kernel(
    const float* __restrict__ x, const _Float16* __restrict__ wh,
    const float* __restrict__ bfp, float* __restrict__ out) {
  // LDS map (bytes). Row strides padded to keep 16B alignment + low conflicts.
  __shared__ __align__(16) char lds[133120];
  _Float16* Xt = (_Float16*)(lds);            // [128][136]  X^T: row (p*32+d), col c
  _Float16* Kt = (_Float16*)(lds + 34816);    // [128][136]  K^T; later U^T; later ot
  _Float16* Qt = (_Float16*)(lds + 69632);    // [128][136]  Q^T
  float*    Sm = (float*)(lds + 104448);      // [128][36]   S^T: row (p*32+j), col i
  _Float16* At = (_Float16*)(lds + 122880);   // [128][40]   A^T: row (p*32+j), col i
  float*    ot = (float*)(lds + 34816);       // [128][132]  out staging [o][j*4+p]

  const int tid  = threadIdx.x;
  const int lane = tid & 63;
  const int wv   = tid >> 6;
  const int quad = lane >> 4;
  const int l15  = lane & 15;
  const int mi   = wv & 7;   // 16-row M-stripe for 128-row GEMMs
  const int ni   = wv >> 3;  // 64-col N-half

  // persistent register weight fragments (A-operand layout: m=l15, k=quad*8+j)
  f16x8 wk[4], wq[4], wp[4];
  {
    const int wrow = (mi*16 + l15) * 128;
#pragma unroll
    for (int kk = 0; kk < 4; ++kk) {
      const int off = wrow + kk*32 + quad*8;
      wk[kk] = *(const f16x8*)(wh + off);
      wq[kk] = *(const f16x8*)(wh + 16384 + off);
      wp[kk] = *(const f16x8*)(wh + 32768 + off);
    }
  }
  const f32x4 bk4 = *(const f32x4*)(bfp +       mi*16 + quad*4);
  const f32x4 bq4 = *(const f32x4*)(bfp + 128 + mi*16 + quad*4);
  const f32x4 bp4 = *(const f32x4*)(bfp + 256 + mi*16 + quad*4);
  const f32x4 zz = {0.f, 0.f, 0.f, 0.f};

  for (int k8 = 0; k8 < 8; ++k8) {
    const int g   = blockIdx.x * 8 + k8;       // pixel-group id, 2048 total
    const int b   = g >> 10;
    const int rem = g & 1023;
    const int h   = rem >> 4;
    const int wg  = rem & 15;                  // w0 = wg*4
    const size_t pbase = (size_t)b * 16777216u + (size_t)(h*64 + wg*4);

    // ---- 1. global x (fp32, float4 along w) -> Xt f16 [p*32+d][c] ----
#pragma unroll
    for (int it = 0; it < 4; ++it) {
      const int e = tid + it*1024;             // (c,d) pair
      const int c = e >> 5, d = e & 31;
      const f32x4 v = *(const f32x4*)(x + pbase + (size_t)c*131072 + d*4096);
      const int rb = d*136 + c;
      Xt[rb]         = (_Float16)v[0];
      Xt[rb + 4352]  = (_Float16)v[1];         // +32*136
      Xt[rb + 8704]  = (_Float16)v[2];
      Xt[rb + 13056] = (_Float16)v[3];
    }
    __syncthreads();

    // ---- 2. GEMM1: K~ = Wk~·X + bk~, Q = Wq·X + bq  (M=128,N=128,K=128) ----
    {
      f32x4 aK[4] = {zz, zz, zz, zz};
      f32x4 aQ[4] = {zz, zz, zz, zz};
#pragma unroll
      for (int kk = 0; kk < 4; ++kk) {
        const int co = kk*32 + quad*8;
        f16x8 bfv[4];
#pragma unroll
        for (int nt = 0; nt < 4; ++nt)
          bfv[nt] = *(const f16x8*)(Xt + (ni*64 + nt*16 + l15)*136 + co);
#pragma unroll
        for (int nt = 0; nt < 4; ++nt) {
          aK[nt] = MFMA(wk[kk], bfv[nt], aK[nt]);
          aQ[nt] = MFMA(wq[kk], bfv[nt], aQ[nt]);
        }
      }
#pragma unroll
      for (int nt = 0; nt < 4; ++nt) {
        const int ad = (ni*64 + nt*16 + l15)*136 + mi*16 + quad*4;
        *(f16x4*)(Kt + ad) = cvt4(aK[nt], bk4);
        *(f16x4*)(Qt + ad) = cvt4(aQ[nt], bq4);
      }
    }
    __syncthreads();

    // ---- 3. S = K~^T · Q per pixel (M=N=32, K=128); store S^T in Sm ----
    {
      const int p = wv >> 2, ti = (wv >> 1) & 1, tj = wv & 1;
      f32x4 aS = zz;
#pragma unroll
      for (int kk = 0; kk < 4; ++kk) {
        const int co = kk*32 + quad*8;
        const f16x8 ak = *(const f16x8*)(Kt + (p*32 + ti*16 + l15)*136 + co);
        const f16x8 bq_ = *(const f16x8*)(Qt + (p*32 + tj*16 + l15)*136 + co);
        aS = MFMA(ak, bq_, aS);
      }
      // D: row=i (quad*4+r), col=j (l15) -> Sm[p*32+j][i], f32x4 along i
      *(f32x4*)(Sm + (p*32 + tj*16 + l15)*36 + ti*16 + quad*4) = aS;
    }
    __syncthreads();

    // ---- 4. softmax over i for each (p,j); write A^T f16 [p*32+j][i] ----
    if (tid < 128) {
      const float* srow = Sm + tid*36;
      float mx = srow[0];
#pragma unroll
      for (int i = 1; i < 32; ++i) mx = fmaxf(mx, srow[i]);
      float den = 0.f;
#pragma unroll
      for (int i = 0; i < 32; ++i) den += __expf(srow[i] - mx);
      const float rr = 1.0f / den;
      _Float16* arow = At + tid*40;
#pragma unroll
      for (int i = 0; i < 32; ++i) arow[i] = (_Float16)(__expf(srow[i] - mx) * rr);
    }
    __syncthreads();

    // ---- 5. U = X·A per pixel (M=128,N=32,K=32); U^T -> Kt (K dead) ----
    {
      const int p = wv & 3, mg = wv >> 2;      // 2 c-stripes per wave
      f16x8 bA[2];
#pragma unroll
      for (int tj = 0; tj < 2; ++tj)
        bA[tj] = *(const f16x8*)(At + (p*32 + tj*16 + l15)*40 + quad*8);
#pragma unroll
      for (int t2 = 0; t2 < 2; ++t2) {
        const int ms = mg*2 + t2;
        const int cbase = (p*32 + quad*8)*136 + ms*16 + l15;  // X[c][i] gather
        const f16x8 ax = { Xt[cbase], Xt[cbase+136], Xt[cbase+272], Xt[cbase+408],
                           Xt[cbase+544], Xt[cbase+680], Xt[cbase+816], Xt[cbase+952] };
#pragma unroll
        for (int tj = 0; tj < 2; ++tj) {
          f32x4 aU = MFMA(ax, bA[tj], zz);
          *(f16x4*)(Kt + (p*32 + tj*16 + l15)*136 + ms*16 + quad*4) = cvt4z(aU);
        }
      }
    }
    __syncthreads();

    // ---- 6. out = Wv'·U + b' (M=128,N=128,K=128), B = U^T in Kt ----
    f32x4 aO[4] = {zz, zz, zz, zz};
#pragma unroll
    for (int kk = 0; kk < 4; ++kk) {
      const int co = kk*32 + quad*8;
      f16x8 bfv[4];
#pragma unroll
      for (int nt = 0; nt < 4; ++nt)
        bfv[nt] = *(const f16x8*)(Kt + (ni*64 + nt*16 + l15)*136 + co);
#pragma unroll
      for (int nt = 0; nt < 4; ++nt)
        aO[nt] = MFMA(wp[kk], bfv[nt], aO[nt]);
    }
    __syncthreads();   // all U^T reads done before ot overwrites Kt/Qt

    // ---- 7. stage fp32 result: ot[o][j*4+p] ----
#pragma unroll
    for (int nt = 0; nt < 4; ++nt) {
      const int col = ni*64 + nt*16 + l15;     // n = p*32 + j
      const int pp = col >> 5, jj = col & 31;
      float* dst = ot + (mi*16 + quad*4)*132 + jj*4 + pp;
      dst[0]   = aO[nt][0] + bp4[0];
      dst[132] = aO[nt][1] + bp4[1];
      dst[264] = aO[nt][2] + bp4[2];
      dst[396] = aO[nt][3] + bp4[3];
    }
    __syncthreads();

    // ---- 8. residual (fp32 from global, L2-hot) + coalesced store ----
#pragma unroll
    for (int it = 0; it < 4; ++it) {
      const int o = it*32 + (tid >> 5);
      const int j = tid & 31;
      const size_t goff = pbase + (size_t)o*131072 + j*4096;
      const f32x4 res = *(const f32x4*)(x + goff);
      f32x4 v = *(const f32x4*)(ot + o*132 + j*4);
      v[0] += res[0]; v[1] += res[1]; v[2] += res[2]; v[3] += res[3];
      *(f32x4*)(out + goff) = v;
    }
    __syncthreads();
  }
}

extern "C" void kernel_launch(void* const* d_in, const int* in_sizes, int n_in,
                              void* d_out, int out_size, void* d_ws, size_t ws_size,
                              hipStream_t stream) {
  const float* x  = (const float*)d_in[0];
  const float* Wk = (const float*)d_in[1];
  const float* bk = (const float*)d_in[2];
  const float* Wq = (const float*)d_in[3];
  const float* bq = (const float*)d_in[4];
  const float* Wv = (const float*)d_in[5];
  const float* bv = (const float*)d_in[6];
  const float* Wo = (const float*)d_in[7];
  const float* bo = (const float*)d_in[8];
  float* out = (float*)d_out;
  _Float16* wh = (_Float16*)d_ws;
  float* bf = (float*)((char*)d_ws + 98304);

  prep_kernel<<<dim3(128), dim3(128), 0, stream>>>(Wk, bk, Wq, bq, Wv, bv, Wo, bo, wh, bf);
  attn_kernel<<<dim3(256), dim3(1024), 0, stream>>>(x, wh, bf, out);
}

// Round 2
// 380.054 us; speedup vs baseline: 1.7929x; 1.7929x over previous
//
#include <hip/hip_runtime.h>

typedef _Float16 f16x8 __attribute__((ext_vector_type(8)));
typedef _Float16 f16x4 __attribute__((ext_vector_type(4)));
typedef float    f32x4 __attribute__((ext_vector_type(4)));

#define MFMA(a,b,c) __builtin_amdgcn_mfma_f32_16x16x32_f16((a),(b),(c),0,0,0)

// ws layout (bytes): [0)       Wk~ f16 [128][128]  (scale folded)
//                    [32768)   Wq  f16 [128][128]
//                    [65536)   Wv' f16 [128][128]  (Wo @ Wv)
//                    [98304)   biases f32: bk~[128], bq[128], b'[128]
//                    [131072)  Xg f16 [2048 groups][128 rows=(p*32+d)][128 c]  (67.1 MB)

// ---------------- prep: fold weights ----------------
__global__ __launch_bounds__(128) void prep_kernel(
    const float* __restrict__ Wk, const float* __restrict__ bk,
    const float* __restrict__ Wq, const float* __restrict__ bq,
    const float* __restrict__ Wv, const float* __restrict__ bv,
    const float* __restrict__ Wo, const float* __restrict__ bo,
    _Float16* __restrict__ wh, float* __restrict__ bf) {
  __shared__ float worow[128];
  const int o = blockIdx.x;
  const int c = threadIdx.x;
  const float scale = 0.08838834764831844f;  // 1/sqrt(128)
  worow[c] = Wo[o*128 + c];
  __syncthreads();
  float acc = 0.f, a2 = 0.f;
  for (int m = 0; m < 128; ++m) {
    acc += worow[m] * Wv[m*128 + c];   // coalesced over c
    a2  += worow[m] * bv[m];           // broadcast
  }
  wh[o*128+c]         = (_Float16)(Wk[o*128+c] * scale);
  wh[16384 + o*128+c] = (_Float16)(Wq[o*128+c]);
  wh[32768 + o*128+c] = (_Float16)acc;
  if (c == 0) {
    bf[o]       = bk[o] * scale;
    bf[128 + o] = bq[o];
    bf[256 + o] = a2 + bo[o];
  }
}

// ---------------- transpose: x fp32 [b,c,d,h,w] -> Xg f16 [g][p*32+d][c] ----------------
// grid = B*D*H = 4096 blocks, 256 thr. Block handles fixed (b,d,h): tile c(128) x w(64).
__global__ __launch_bounds__(256) void transpose_kernel(
    const float* __restrict__ x, _Float16* __restrict__ Xg) {
  __shared__ _Float16 Lt[64 * 130];          // [w][c], stride 130 breaks conflicts
  const int bid = blockIdx.x;
  const int h = bid & 63, d = (bid >> 6) & 31, b = bid >> 11;
  const int tid = threadIdx.x;
  const size_t rbase = (size_t)b*16777216u + (size_t)d*4096 + h*64;
  // read: full 256B w-rows, convert to f16, scatter into Lt[w][c]
#pragma unroll
  for (int i = 0; i < 8; ++i) {
    const int chunk = tid + i*256;           // 0..2047
    const int c = chunk >> 4, wq = chunk & 15;
    const f32x4 v = *(const f32x4*)(x + rbase + (size_t)c*131072 + wq*4);
    Lt[(wq*4+0)*130 + c] = (_Float16)v[0];
    Lt[(wq*4+1)*130 + c] = (_Float16)v[1];
    Lt[(wq*4+2)*130 + c] = (_Float16)v[2];
    Lt[(wq*4+3)*130 + c] = (_Float16)v[3];
  }
  __syncthreads();
  // write: per w-row, 128 c contiguous (256B segments, fully line-aligned)
  const int gbase = b*1024 + h*16;
#pragma unroll
  for (int i = 0; i < 4; ++i) {
    const int idx = tid + i*256;             // 0..1023
    const int w = idx >> 4, ck = (idx & 15) * 8;
    const int wg = w >> 2, p = w & 3;
    const f16x8 v = *(const f16x8*)(Lt + w*130 + ck);
    *(f16x8*)(Xg + (size_t)(gbase + wg)*16384 + (p*32 + d)*128 + ck) = v;
  }
}

__device__ __forceinline__ f16x4 cvt4(f32x4 v, f32x4 b) {
  f16x4 r;
  r[0] = (_Float16)(v[0] + b[0]); r[1] = (_Float16)(v[1] + b[1]);
  r[2] = (_Float16)(v[2] + b[2]); r[3] = (_Float16)(v[3] + b[3]);
  return r;
}
__device__ __forceinline__ f16x4 cvt4z(f32x4 v) {
  f16x4 r;
  r[0] = (_Float16)v[0]; r[1] = (_Float16)v[1];
  r[2] = (_Float16)v[2]; r[3] = (_Float16)v[3];
  return r;
}

// ---------------- fused attention ----------------
// grid = 2048 blocks x 1024 thr, ONE pixel-group (4 consecutive w) per block.
// Swizzle: the 4 groups sharing each 64B out-line run concurrently on the same XCD
// (assuming round-robin blockIdx%8 -> XCD), so L2 merges the 16B out-granules.
__global__ __launch_bounds__(1024) void attn_kernel(
    const _Float16* __restrict__ Xg, const _Float16* __restrict__ wh,
    const float* __restrict__ bfp, float* __restrict__ out) {
  __shared__ __align__(16) char lds[133120];
  _Float16* Xt = (_Float16*)(lds);            // [128][136]  X^T: row (p*32+d), col c
  _Float16* Kt = (_Float16*)(lds + 34816);    // [128][136]  K^T; later U^T
  _Float16* Qt = (_Float16*)(lds + 69632);    // [128][136]  Q^T
  float*    Sm = (float*)(lds + 104448);      // [128][36]   S^T
  _Float16* At = (_Float16*)(lds + 122880);   // [128][40]   A^T
  float*    ot = (float*)(lds + 34816);       // [128][132]  out staging [o][j*4+p]

  const int tid  = threadIdx.x;
  const int lane = tid & 63;
  const int wv   = tid >> 6;
  const int quad = lane >> 4;
  const int l15  = lane & 15;
  const int mi   = wv & 7;
  const int ni   = wv >> 3;

  const int bid = blockIdx.x;
  const int g = (bid & ~31) | ((bid & 7) << 2) | ((bid >> 3) & 3);
  const int b   = g >> 10;
  const int rem = g & 1023;
  const int h   = rem >> 4;
  const int wg  = rem & 15;
  const size_t pbase = (size_t)b * 16777216u + (size_t)(h*64 + wg*4);

  // persistent register weight fragments (A-operand layout: m=l15, k=quad*8+j)
  f16x8 wk[4], wq[4], wp[4];
  {
    const int wrow = (mi*16 + l15) * 128;
#pragma unroll
    for (int kk = 0; kk < 4; ++kk) {
      const int off = wrow + kk*32 + quad*8;
      wk[kk] = *(const f16x8*)(wh + off);
      wq[kk] = *(const f16x8*)(wh + 16384 + off);
      wp[kk] = *(const f16x8*)(wh + 32768 + off);
    }
  }
  const f32x4 bk4 = *(const f32x4*)(bfp +       mi*16 + quad*4);
  const f32x4 bq4 = *(const f32x4*)(bfp + 128 + mi*16 + quad*4);
  const f32x4 bp4 = *(const f32x4*)(bfp + 256 + mi*16 + quad*4);
  const f32x4 zz = {0.f, 0.f, 0.f, 0.f};

  // ---- 1. coalesced load of this group's 32KB f16 chunk -> Xt (padded) ----
  {
    const _Float16* src = Xg + (size_t)g * 16384;
#pragma unroll
    for (int i = 0; i < 2; ++i) {
      const int idx = tid + i*1024;          // 0..2047
      const int row = idx >> 4, ck = (idx & 15) * 8;
      const f16x8 v = *(const f16x8*)(src + row*128 + ck);
      *(f16x8*)(Xt + row*136 + ck) = v;
    }
  }
  __syncthreads();

  // ---- 2. GEMM1: K~ = Wk~·X + bk~, Q = Wq·X + bq ----
  {
    f32x4 aK[4] = {zz, zz, zz, zz};
    f32x4 aQ[4] = {zz, zz, zz, zz};
#pragma unroll
    for (int kk = 0; kk < 4; ++kk) {
      const int co = kk*32 + quad*8;
      f16x8 bfv[4];
#pragma unroll
      for (int nt = 0; nt < 4; ++nt)
        bfv[nt] = *(const f16x8*)(Xt + (ni*64 + nt*16 + l15)*136 + co);
#pragma unroll
      for (int nt = 0; nt < 4; ++nt) {
        aK[nt] = MFMA(wk[kk], bfv[nt], aK[nt]);
        aQ[nt] = MFMA(wq[kk], bfv[nt], aQ[nt]);
      }
    }
#pragma unroll
    for (int nt = 0; nt < 4; ++nt) {
      const int ad = (ni*64 + nt*16 + l15)*136 + mi*16 + quad*4;
      *(f16x4*)(Kt + ad) = cvt4(aK[nt], bk4);
      *(f16x4*)(Qt + ad) = cvt4(aQ[nt], bq4);
    }
  }
  __syncthreads();

  // ---- 3. S = K~^T · Q per pixel; store S^T in Sm ----
  {
    const int p = wv >> 2, ti = (wv >> 1) & 1, tj = wv & 1;
    f32x4 aS = zz;
#pragma unroll
    for (int kk = 0; kk < 4; ++kk) {
      const int co = kk*32 + quad*8;
      const f16x8 ak  = *(const f16x8*)(Kt + (p*32 + ti*16 + l15)*136 + co);
      const f16x8 bq_ = *(const f16x8*)(Qt + (p*32 + tj*16 + l15)*136 + co);
      aS = MFMA(ak, bq_, aS);
    }
    *(f32x4*)(Sm + (p*32 + tj*16 + l15)*36 + ti*16 + quad*4) = aS;
  }
  __syncthreads();

  // ---- 4. softmax over i for each (p,j) ----
  if (tid < 128) {
    const float* srow = Sm + tid*36;
    float mx = srow[0];
#pragma unroll
    for (int i = 1; i < 32; ++i) mx = fmaxf(mx, srow[i]);
    float den = 0.f;
#pragma unroll
    for (int i = 0; i < 32; ++i) den += __expf(srow[i] - mx);
    const float rr = 1.0f / den;
    _Float16* arow = At + tid*40;
#pragma unroll
    for (int i = 0; i < 32; ++i) arow[i] = (_Float16)(__expf(srow[i] - mx) * rr);
  }
  __syncthreads();

  // ---- 5. U = X·A per pixel; U^T -> Kt (K dead) ----
  {
    const int p = wv & 3, mg = wv >> 2;
    f16x8 bA[2];
#pragma unroll
    for (int tj = 0; tj < 2; ++tj)
      bA[tj] = *(const f16x8*)(At + (p*32 + tj*16 + l15)*40 + quad*8);
#pragma unroll
    for (int t2 = 0; t2 < 2; ++t2) {
      const int ms = mg*2 + t2;
      const int cbase = (p*32 + quad*8)*136 + ms*16 + l15;
      const f16x8 ax = { Xt[cbase], Xt[cbase+136], Xt[cbase+272], Xt[cbase+408],
                         Xt[cbase+544], Xt[cbase+680], Xt[cbase+816], Xt[cbase+952] };
#pragma unroll
      for (int tj = 0; tj < 2; ++tj) {
        f32x4 aU = MFMA(ax, bA[tj], zz);
        *(f16x4*)(Kt + (p*32 + tj*16 + l15)*136 + ms*16 + quad*4) = cvt4z(aU);
      }
    }
  }
  __syncthreads();

  // ---- 6. out = Wv'·U + b' ----
  f32x4 aO[4] = {zz, zz, zz, zz};
#pragma unroll
  for (int kk = 0; kk < 4; ++kk) {
    const int co = kk*32 + quad*8;
    f16x8 bfv[4];
#pragma unroll
    for (int nt = 0; nt < 4; ++nt)
      bfv[nt] = *(const f16x8*)(Kt + (ni*64 + nt*16 + l15)*136 + co);
#pragma unroll
    for (int nt = 0; nt < 4; ++nt)
      aO[nt] = MFMA(wp[kk], bfv[nt], aO[nt]);
  }
  __syncthreads();   // all U^T reads done before ot overwrites Kt/Qt

  // ---- 7. stage fp32 result: ot[o][j*4+p] ----
#pragma unroll
  for (int nt = 0; nt < 4; ++nt) {
    const int col = ni*64 + nt*16 + l15;
    const int pp = col >> 5, jj = col & 31;
    float* dst = ot + (mi*16 + quad*4)*132 + jj*4 + pp;
    dst[0]   = aO[nt][0] + bp4[0];
    dst[132] = aO[nt][1] + bp4[1];
    dst[264] = aO[nt][2] + bp4[2];
    dst[396] = aO[nt][3] + bp4[3];
  }
  __syncthreads();

  // ---- 8. residual from Xt (f16) + store ----
#pragma unroll
  for (int it = 0; it < 4; ++it) {
    const int o = it*32 + (tid >> 5);
    const int j = tid & 31;
    f32x4 v = *(const f32x4*)(ot + o*132 + j*4);
    v[0] += (float)Xt[(0*32 + j)*136 + o];
    v[1] += (float)Xt[(1*32 + j)*136 + o];
    v[2] += (float)Xt[(2*32 + j)*136 + o];
    v[3] += (float)Xt[(3*32 + j)*136 + o];
    *(f32x4*)(out + pbase + (size_t)o*131072 + j*4096) = v;
  }
}

extern "C" void kernel_launch(void* const* d_in, const int* in_sizes, int n_in,
                              void* d_out, int out_size, void* d_ws, size_t ws_size,
                              hipStream_t stream) {
  const float* x  = (const float*)d_in[0];
  const float* Wk = (const float*)d_in[1];
  const float* bk = (const float*)d_in[2];
  const float* Wq = (const float*)d_in[3];
  const float* bq = (const float*)d_in[4];
  const float* Wv = (const float*)d_in[5];
  const float* bv = (const float*)d_in[6];
  const float* Wo = (const float*)d_in[7];
  const float* bo = (const float*)d_in[8];
  float* out = (float*)d_out;
  _Float16* wh = (_Float16*)d_ws;
  float* bf = (float*)((char*)d_ws + 98304);
  _Float16* Xg = (_Float16*)((char*)d_ws + 131072);  // needs 67.1 MB of ws

  prep_kernel<<<dim3(128), dim3(128), 0, stream>>>(Wk, bk, Wq, bq, Wv, bv, Wo, bo, wh, bf);
  transpose_kernel<<<dim3(4096), dim3(256), 0, stream>>>(x, Xg);
  attn_kernel<<<dim3(2048), dim3(1024), 0, stream>>>(Xg, wh, bf, out);
}